// Round 1
// baseline (559.045 us; speedup 1.0000x reference)
//
#include <hip/hip_runtime.h>
#include <math.h>

#define B_ 32
#define S_ 2048
#define D_ 1024
#define H_ 16
#define HD_ 64
#define MODES_ 16
#define EPS_ 1e-5f

// workspace float offsets
#define OFF_FILT_RE 0
#define OFF_FILT_IM 16
#define OFF_CK      32
#define OFF_QK      1024            // B*H*D = 524288
#define OFF_SC      525312          // B*H*S = 1048576 (scores -> attn in place)
#define OFF_PART    1573888         // 8*B*H*D = 4194304
#define OFF_XCTX    5768192         // B*H*D
#define OFF_CTX     6292480         // B*D
#define OFF_R1      6325248
#define OFF_Z1      6358016
#define OFF_ZSP     6390784
#define OFF_R2      6423552
#define OFF_Z3      6456320

// ---------------- filt[m] = mean_d(scale_real/imag[m,:]) ----------------
__global__ void k_filt(const float* __restrict__ sr, const float* __restrict__ si, float* __restrict__ ws) {
    int t = threadIdx.x;
    int m = t >> 4, sub = t & 15;
    float ar = 0.f, ai = 0.f;
    for (int k = sub; k < D_; k += 16) { ar += sr[m * D_ + k]; ai += si[m * D_ + k]; }
#pragma unroll
    for (int o = 8; o > 0; o >>= 1) { ar += __shfl_xor(ar, o, 16); ai += __shfl_xor(ai, o, 16); }
    if (sub == 0) {
        ws[OFF_FILT_RE + m] = ar * (1.f / (float)D_);
        ws[OFF_FILT_IM + m] = ai * (1.f / (float)D_);
    }
}

// ---------------- q = z_prev@Wq.T+bq ; qk[b,h,:] = Wk_h.T @ q[b,h] ; cK = q.bk ----------------
__global__ void k_qk(const float* __restrict__ zprev, const float* __restrict__ ipw,
                     const float* __restrict__ ipb, float* __restrict__ ws) {
    int b = blockIdx.x % B_, h = blockIdx.x / B_;
    __shared__ float zrow[D_];
    __shared__ float qs[HD_];
    int t = threadIdx.x;
    for (int i = t; i < D_; i += 256) zrow[i] = zprev[(size_t)b * D_ + i];
    __syncthreads();
    int w = t >> 6, l = t & 63;
    for (int ii = 0; ii < 16; ++ii) {
        int i = w * 16 + ii;
        const float* wr = ipw + (size_t)(h * HD_ + i) * D_;
        float acc = 0.f;
        for (int k = l; k < D_; k += 64) acc += zrow[k] * wr[k];
#pragma unroll
        for (int o = 32; o > 0; o >>= 1) acc += __shfl_xor(acc, o);
        if (l == 0) qs[i] = acc + ipb[h * HD_ + i];
    }
    __syncthreads();
    if (w == 0) {
        float a = qs[l] * ipb[D_ + h * HD_ + l];
#pragma unroll
        for (int o = 32; o > 0; o >>= 1) a += __shfl_xor(a, o);
        if (l == 0) ws[OFF_CK + b * H_ + h] = a;
    }
    const float* wk = ipw + (size_t)D_ * D_ + (size_t)(h * HD_) * D_;
    for (int n = t; n < D_; n += 256) {
        float acc = 0.f;
#pragma unroll
        for (int i = 0; i < HD_; ++i) acc += qs[i] * wk[(size_t)i * D_ + n];
        ws[OFF_QK + (size_t)(b * H_ + h) * D_ + n] = acc;
    }
}

// ---------------- pass 1: scores[b,h,s] = (x[b,s].qk[b,h] + cK)/8 ----------------
#define SROWS 64
#define XROWS 8
__global__ void k_scores(const float* __restrict__ xfeat, float* __restrict__ ws) {
    int bid = blockIdx.x;
    int b = bid / (S_ / SROWS);
    int sc = bid % (S_ / SROWS);
    int s0 = sc * SROWS;
    int t = threadIdx.x, w = t >> 6, l = t & 63;
    __shared__ float xs[XROWS][D_];

    const float* q0 = ws + OFF_QK + (size_t)(b * H_ + w * 4 + 0) * D_;
    const float* q1 = ws + OFF_QK + (size_t)(b * H_ + w * 4 + 1) * D_;
    const float* q2 = ws + OFF_QK + (size_t)(b * H_ + w * 4 + 2) * D_;
    const float* q3 = ws + OFF_QK + (size_t)(b * H_ + w * 4 + 3) * D_;
    float qkr0[16], qkr1[16], qkr2[16], qkr3[16];
#pragma unroll
    for (int k = 0; k < 16; ++k) {
        qkr0[k] = q0[k * 64 + l]; qkr1[k] = q1[k * 64 + l];
        qkr2[k] = q2[k * 64 + l]; qkr3[k] = q3[k * 64 + l];
    }
    float ck0 = ws[OFF_CK + b * H_ + w * 4 + 0];
    float ck1 = ws[OFF_CK + b * H_ + w * 4 + 1];
    float ck2 = ws[OFF_CK + b * H_ + w * 4 + 2];
    float ck3 = ws[OFF_CK + b * H_ + w * 4 + 3];

    for (int r0 = 0; r0 < SROWS; r0 += XROWS) {
        __syncthreads();
        const float4* src = (const float4*)(xfeat + ((size_t)b * S_ + s0 + r0) * D_);
        float4* dst = (float4*)&xs[0][0];
        for (int idx = t; idx < XROWS * D_ / 4; idx += 256) dst[idx] = src[idx];
        __syncthreads();
        for (int r = 0; r < XROWS; ++r) {
            float p0 = 0.f, p1 = 0.f, p2 = 0.f, p3 = 0.f;
#pragma unroll
            for (int k = 0; k < 16; ++k) {
                float xv = xs[r][k * 64 + l];
                p0 += xv * qkr0[k]; p1 += xv * qkr1[k];
                p2 += xv * qkr2[k]; p3 += xv * qkr3[k];
            }
#pragma unroll
            for (int o = 32; o > 0; o >>= 1) {
                p0 += __shfl_xor(p0, o); p1 += __shfl_xor(p1, o);
                p2 += __shfl_xor(p2, o); p3 += __shfl_xor(p3, o);
            }
            if (l < 4) {
                float p = (l == 0) ? (p0 + ck0) : (l == 1) ? (p1 + ck1) : (l == 2) ? (p2 + ck2) : (p3 + ck3);
                int h = w * 4 + l;
                ws[OFF_SC + (size_t)(b * H_ + h) * S_ + (s0 + r0 + r)] = p * 0.125f;
            }
        }
    }
}

// ---------------- softmax over S per (b,h) ----------------
__global__ void k_softmax(float* __restrict__ ws) {
    int t = threadIdx.x, w = t >> 6, l = t & 63;
    float* row = ws + OFF_SC + (size_t)blockIdx.x * S_;
    float4 a = ((float4*)row)[t];
    float4 c = ((float4*)row)[t + 256];
    __shared__ float sred[4];
    float mx = fmaxf(fmaxf(fmaxf(a.x, a.y), fmaxf(a.z, a.w)),
                     fmaxf(fmaxf(c.x, c.y), fmaxf(c.z, c.w)));
#pragma unroll
    for (int o = 32; o > 0; o >>= 1) mx = fmaxf(mx, __shfl_xor(mx, o));
    if (l == 0) sred[w] = mx;
    __syncthreads();
    mx = fmaxf(fmaxf(sred[0], sred[1]), fmaxf(sred[2], sred[3]));
    __syncthreads();
    a.x = __expf(a.x - mx); a.y = __expf(a.y - mx); a.z = __expf(a.z - mx); a.w = __expf(a.w - mx);
    c.x = __expf(c.x - mx); c.y = __expf(c.y - mx); c.z = __expf(c.z - mx); c.w = __expf(c.w - mx);
    float sum = a.x + a.y + a.z + a.w + c.x + c.y + c.z + c.w;
#pragma unroll
    for (int o = 32; o > 0; o >>= 1) sum += __shfl_xor(sum, o);
    if (l == 0) sred[w] = sum;
    __syncthreads();
    sum = sred[0] + sred[1] + sred[2] + sred[3];
    float inv = 1.f / sum;
    a.x *= inv; a.y *= inv; a.z *= inv; a.w *= inv;
    c.x *= inv; c.y *= inv; c.z *= inv; c.w *= inv;
    ((float4*)row)[t] = a; ((float4*)row)[t + 256] = c;
}

// ---------------- pass 2: partial xctx[b,h,:] = sum_s attn * x[b,s,:] ----------------
#define SCH 256
__global__ void k_xctx(const float* __restrict__ xfeat, float* __restrict__ ws) {
    int bid = blockIdx.x;
    int dc = bid & 3, sc = (bid >> 2) & 7, b = bid >> 5;
    int t = threadIdx.x, dg = t & 63, hg = t >> 6;
    int s0 = sc * SCH;
    __shared__ float wsm[SCH][16];
    const float* attn = ws + OFF_SC;
    for (int idx = t; idx < SCH * H_; idx += 256) {
        int h = idx >> 8;
        int s = idx & 255;
        wsm[s][h] = attn[(size_t)(b * H_ + h) * S_ + s0 + s];
    }
    __syncthreads();
    int d0 = dc * 256 + dg * 4;
    float4 acc0 = {0, 0, 0, 0}, acc1 = {0, 0, 0, 0}, acc2 = {0, 0, 0, 0}, acc3 = {0, 0, 0, 0};
    const float* xp = xfeat + ((size_t)b * S_ + s0) * D_ + d0;
    for (int s = 0; s < SCH; ++s) {
        float4 xv = *(const float4*)(xp + (size_t)s * D_);
        float4 wv = *(const float4*)&wsm[s][hg * 4];
        acc0.x += wv.x * xv.x; acc0.y += wv.x * xv.y; acc0.z += wv.x * xv.z; acc0.w += wv.x * xv.w;
        acc1.x += wv.y * xv.x; acc1.y += wv.y * xv.y; acc1.z += wv.y * xv.z; acc1.w += wv.y * xv.w;
        acc2.x += wv.z * xv.x; acc2.y += wv.z * xv.y; acc2.z += wv.z * xv.z; acc2.w += wv.z * xv.w;
        acc3.x += wv.w * xv.x; acc3.y += wv.w * xv.y; acc3.z += wv.w * xv.z; acc3.w += wv.w * xv.w;
    }
    float* pp = ws + OFF_PART + (((size_t)sc * B_ + b) * H_ + hg * 4) * D_ + d0;
    *(float4*)(pp) = acc0;
    *(float4*)(pp + D_) = acc1;
    *(float4*)(pp + 2 * D_) = acc2;
    *(float4*)(pp + 3 * D_) = acc3;
}

__global__ void k_xctx_reduce(float* __restrict__ ws) {
    int idx = blockIdx.x * 256 + threadIdx.x;
    float a = 0.f;
#pragma unroll
    for (int sc = 0; sc < 8; ++sc) a += ws[OFF_PART + (size_t)sc * (B_ * H_ * D_) + idx];
    ws[OFF_XCTX + idx] = a;
}

// ---------------- ctx[b, h*64+j] = Wv_h[j,:].xctx[b,h,:] + bv ----------------
__global__ void k_ctx(const float* __restrict__ ipw, const float* __restrict__ ipb, float* __restrict__ ws) {
    int b = blockIdx.x % B_, h = blockIdx.x / B_;
    __shared__ float xr[D_];
    int t = threadIdx.x;
    for (int i = t; i < D_; i += 256) xr[i] = ws[OFF_XCTX + (size_t)(b * H_ + h) * D_ + i];
    __syncthreads();
    int w = t >> 6, l = t & 63;
    for (int jj = 0; jj < 16; ++jj) {
        int j = w * 16 + jj;
        const float* wr = ipw + ((size_t)2 * D_ + h * HD_ + j) * D_;
        float acc = 0.f;
        for (int k = l; k < D_; k += 64) acc += xr[k] * wr[k];
#pragma unroll
        for (int o = 32; o > 0; o >>= 1) acc += __shfl_xor(acc, o);
        if (l == 0) ws[OFF_CTX + (size_t)b * D_ + h * HD_ + j] = acc + ipb[2 * D_ + h * HD_ + j];
    }
}

// ---------------- out = resid + scale*(invec @ W.T + bias)  (per-b row chunk) ----------------
__global__ void k_proj_res(const float* __restrict__ wmat, const float* __restrict__ bias,
                           const float* __restrict__ scale, const float* __restrict__ resid,
                           const float* __restrict__ invec, float* __restrict__ outvec) {
    int b = blockIdx.x >> 2, nc = blockIdx.x & 3;
    __shared__ float cx[D_];
    int t = threadIdx.x;
    for (int i = t; i < D_; i += 256) cx[i] = invec[(size_t)b * D_ + i];
    __syncthreads();
    int n = nc * 256 + t;
    const float4* wr = (const float4*)(wmat + (size_t)n * D_);
    float acc = 0.f;
    for (int k = 0; k < D_ / 4; ++k) {
        float4 wv = wr[k];
        float4 cv = *(const float4*)&cx[4 * k];
        acc += cv.x * wv.x + cv.y * wv.y + cv.z * wv.z + cv.w * wv.w;
    }
    outvec[(size_t)b * D_ + n] = resid[(size_t)b * D_ + n] + scale[0] * (acc + bias[n]);
}

// ---------------- layernorm over D (per b) ----------------
__global__ void k_ln(const float* __restrict__ inv, const float* __restrict__ g,
                     const float* __restrict__ bv, float* __restrict__ outv) {
    int b = blockIdx.x, t = threadIdx.x, w = t >> 6, l = t & 63;
    float4 v = ((const float4*)(inv + (size_t)b * D_))[t];
    float s = v.x + v.y + v.z + v.w;
    float s2 = v.x * v.x + v.y * v.y + v.z * v.z + v.w * v.w;
    __shared__ float sa[4], sb[4];
#pragma unroll
    for (int o = 32; o > 0; o >>= 1) { s += __shfl_xor(s, o); s2 += __shfl_xor(s2, o); }
    if (l == 0) { sa[w] = s; sb[w] = s2; }
    __syncthreads();
    s = sa[0] + sa[1] + sa[2] + sa[3];
    s2 = sb[0] + sb[1] + sb[2] + sb[3];
    float mu = s * (1.f / (float)D_);
    float var = s2 * (1.f / (float)D_) - mu * mu;
    float rs = rsqrtf(var + EPS_);
    float4 gg = ((const float4*)g)[t], bb = ((const float4*)bv)[t];
    float4 o4;
    o4.x = (v.x - mu) * rs * gg.x + bb.x;
    o4.y = (v.y - mu) * rs * gg.y + bb.y;
    o4.z = (v.z - mu) * rs * gg.z + bb.z;
    o4.w = (v.w - mu) * rs * gg.w + bb.w;
    ((float4*)(outv + (size_t)b * D_))[t] = o4;
}

// ---------------- spectral: 16-mode DFT of z1, filter, synthesize ----------------
__global__ void k_spec(float* __restrict__ ws) {
    int b = blockIdx.x, t = threadIdx.x;
    __shared__ float zr[D_];
    __shared__ float cre[MODES_], cim[MODES_];
    const float* z1 = ws + OFF_Z1 + (size_t)b * D_;
    for (int i = t; i < D_; i += 256) zr[i] = z1[i];
    __syncthreads();
    const float step = 6.283185307179586f / (float)D_;
    int m = t >> 4, sub = t & 15;
    float ar = 0.f, ai = 0.f;
    for (int n = sub; n < D_; n += 16) {
        int idx = (m * n) & (D_ - 1);
        float sn, cs;
        __sincosf(step * (float)idx, &sn, &cs);
        float z = zr[n];
        ar += z * cs; ai -= z * sn;
    }
#pragma unroll
    for (int o = 8; o > 0; o >>= 1) { ar += __shfl_xor(ar, o, 16); ai += __shfl_xor(ai, o, 16); }
    if (sub == 0) {
        float fr = ws[OFF_FILT_RE + m], fi = ws[OFF_FILT_IM + m];
        cre[m] = (fr * ar - fi * ai) * (1.f / (float)D_);
        cim[m] = (fr * ai + fi * ar) * (1.f / (float)D_);
    }
    __syncthreads();
    for (int n = t; n < D_; n += 256) {
        float acc = 0.f;
#pragma unroll
        for (int mm = 0; mm < MODES_; ++mm) {
            int idx = (mm * n) & (D_ - 1);
            float sn, cs;
            __sincosf(step * (float)idx, &sn, &cs);
            acc += cre[mm] * cs - cim[mm] * sn;
        }
        ws[OFF_ZSP + (size_t)b * D_ + n] = acc;
    }
}

// ---------------- LN2 + gate mix -> z3 ----------------
__global__ void k_ln2gate(const float* __restrict__ zprev, const float* __restrict__ g2,
                          const float* __restrict__ b2v, const float* __restrict__ gate,
                          float* __restrict__ ws) {
    int b = blockIdx.x, t = threadIdx.x, w = t >> 6, l = t & 63;
    float4 v = ((const float4*)(ws + OFF_R2 + (size_t)b * D_))[t];
    float s = v.x + v.y + v.z + v.w;
    float s2 = v.x * v.x + v.y * v.y + v.z * v.z + v.w * v.w;
    __shared__ float sa[4], sb[4];
#pragma unroll
    for (int o = 32; o > 0; o >>= 1) { s += __shfl_xor(s, o); s2 += __shfl_xor(s2, o); }
    if (l == 0) { sa[w] = s; sb[w] = s2; }
    __syncthreads();
    s = sa[0] + sa[1] + sa[2] + sa[3];
    s2 = sb[0] + sb[1] + sb[2] + sb[3];
    float mu = s * (1.f / (float)D_);
    float var = s2 * (1.f / (float)D_) - mu * mu;
    float rs = rsqrtf(var + EPS_);
    float4 gg = ((const float4*)g2)[t], bb = ((const float4*)b2v)[t];
    float gsig = 1.f / (1.f + __expf(-gate[0]));
    float4 zp = ((const float4*)(zprev + (size_t)b * D_))[t];
    float4 z3;
    z3.x = gsig * ((v.x - mu) * rs * gg.x + bb.x) + (1.f - gsig) * zp.x;
    z3.y = gsig * ((v.y - mu) * rs * gg.y + bb.y) + (1.f - gsig) * zp.y;
    z3.z = gsig * ((v.z - mu) * rs * gg.z + bb.z) + (1.f - gsig) * zp.z;
    z3.w = gsig * ((v.w - mu) * rs * gg.w + bb.w) + (1.f - gsig) * zp.w;
    ((float4*)(ws + OFF_Z3 + (size_t)b * D_))[t] = z3;
}

// ---------------- batchnorm over B per column ----------------
__global__ void k_bn(const float* __restrict__ bng, const float* __restrict__ bnb,
                     const float* __restrict__ ws, float* __restrict__ out) {
    int d = blockIdx.x * 256 + threadIdx.x;
    float vals[B_];
    float s = 0.f, s2 = 0.f;
#pragma unroll
    for (int b = 0; b < B_; ++b) {
        float v = ws[OFF_Z3 + (size_t)b * D_ + d];
        vals[b] = v; s += v; s2 += v * v;
    }
    float mu = s * (1.f / (float)B_);
    float var = s2 * (1.f / (float)B_) - mu * mu;
    float rs = rsqrtf(var + EPS_);
    float gg = bng[d], bb = bnb[d];
#pragma unroll
    for (int b = 0; b < B_; ++b) out[(size_t)b * D_ + d] = (vals[b] - mu) * rs * gg + bb;
}

extern "C" void kernel_launch(void* const* d_in, const int* in_sizes, int n_in,
                              void* d_out, int out_size, void* d_ws, size_t ws_size,
                              hipStream_t stream) {
    const float* x_feat = (const float*)d_in[0];
    const float* z_prev = (const float*)d_in[1];
    const float* ipw    = (const float*)d_in[2];
    const float* ipb    = (const float*)d_in[3];
    const float* wout   = (const float*)d_in[4];
    const float* bout   = (const float*)d_in[5];
    const float* ln1g   = (const float*)d_in[6];
    const float* ln1b   = (const float*)d_in[7];
    const float* ln2g   = (const float*)d_in[8];
    const float* ln2b   = (const float*)d_in[9];
    const float* sreal  = (const float*)d_in[10];
    const float* simag  = (const float*)d_in[11];
    const float* pw     = (const float*)d_in[12];
    const float* pb     = (const float*)d_in[13];
    const float* bng    = (const float*)d_in[14];
    const float* bnb    = (const float*)d_in[15];
    const float* gate   = (const float*)d_in[16];
    const float* sattn  = (const float*)d_in[17];
    const float* sden   = (const float*)d_in[18];
    float* ws  = (float*)d_ws;
    float* out = (float*)d_out;

    k_filt<<<1, 256, 0, stream>>>(sreal, simag, ws);
    k_qk<<<B_ * H_, 256, 0, stream>>>(z_prev, ipw, ipb, ws);
    k_scores<<<B_ * (S_ / SROWS), 256, 0, stream>>>(x_feat, ws);
    k_softmax<<<B_ * H_, 256, 0, stream>>>(ws);
    k_xctx<<<B_ * 4 * 8, 256, 0, stream>>>(x_feat, ws);
    k_xctx_reduce<<<(B_ * H_ * D_) / 256, 256, 0, stream>>>(ws);
    k_ctx<<<B_ * H_, 256, 0, stream>>>(ipw, ipb, ws);
    k_proj_res<<<B_ * 4, 256, 0, stream>>>(wout, bout, sattn, z_prev, ws + OFF_CTX, ws + OFF_R1);
    k_ln<<<B_, 256, 0, stream>>>(ws + OFF_R1, ln1g, ln1b, ws + OFF_Z1);
    k_spec<<<B_, 256, 0, stream>>>(ws);
    k_proj_res<<<B_ * 4, 256, 0, stream>>>(pw, pb, sden, ws + OFF_Z1, ws + OFF_ZSP, ws + OFF_R2);
    k_ln2gate<<<B_, 256, 0, stream>>>(z_prev, ln2g, ln2b, gate, ws);
    k_bn<<<D_ / 256, 256, 0, stream>>>(bng, bnb, ws, out);
}

// Round 2
// 333.634 us; speedup vs baseline: 1.6756x; 1.6756x over previous
//
#include <hip/hip_runtime.h>
#include <math.h>

#define B_ 32
#define S_ 2048
#define D_ 1024
#define H_ 16
#define HD_ 64
#define MODES_ 16
#define EPS_ 1e-5f

// workspace float offsets
#define OFF_FILT_RE 0
#define OFF_FILT_IM 16
#define OFF_CK      32
#define OFF_QK      1024            // B*H*D = 524288
#define OFF_SC      525312          // B*H*S = 1048576 (scores -> attn in place)
#define OFF_Q       525312          // alias: q[b,n] lives here until k_scores overwrites
#define OFF_PART    1573888         // 8*B*H*D = 4194304
#define OFF_XCTX    5768192         // B*H*D
#define OFF_CTX     6292480         // B*D
#define OFF_R1      6325248
#define OFF_Z1      6358016
#define OFF_ZSP     6390784
#define OFF_R2      6423552
#define OFF_Z3      6456320

// ---------------- filt[m] = mean_d(scale_real/imag[m,:]) ; one block per mode ----------------
__global__ void k_filt(const float* __restrict__ sr, const float* __restrict__ si, float* __restrict__ ws) {
    int m = blockIdx.x, t = threadIdx.x, w = t >> 6, l = t & 63;
    float4 a = ((const float4*)(sr + (size_t)m * D_))[t];
    float4 b = ((const float4*)(si + (size_t)m * D_))[t];
    float ar = a.x + a.y + a.z + a.w;
    float ai = b.x + b.y + b.z + b.w;
    __shared__ float sa[4], sb[4];
#pragma unroll
    for (int o = 32; o > 0; o >>= 1) { ar += __shfl_xor(ar, o); ai += __shfl_xor(ai, o); }
    if (l == 0) { sa[w] = ar; sb[w] = ai; }
    __syncthreads();
    if (t == 0) {
        ws[OFF_FILT_RE + m] = (sa[0] + sa[1] + sa[2] + sa[3]) * (1.f / (float)D_);
        ws[OFF_FILT_IM + m] = (sb[0] + sb[1] + sb[2] + sb[3]) * (1.f / (float)D_);
    }
}

// ---------------- q[b,n] = z_prev[b,:] . Wq[n,:] + bq[n] ----------------
__global__ void k_q(const float* __restrict__ zprev, const float* __restrict__ ipw,
                    const float* __restrict__ ipb, float* __restrict__ ws) {
    int b = blockIdx.x >> 2, nc = blockIdx.x & 3;
    __shared__ float zr[D_];
    int t = threadIdx.x;
    for (int i = t; i < D_; i += 256) zr[i] = zprev[(size_t)b * D_ + i];
    __syncthreads();
    int n = nc * 256 + t;
    const float4* wr = (const float4*)(ipw + (size_t)n * D_);
    float acc = 0.f;
    for (int k = 0; k < D_ / 4; ++k) {
        float4 wv = wr[k];
        float4 zv = *(const float4*)&zr[4 * k];
        acc += zv.x * wv.x + zv.y * wv.y + zv.z * wv.z + zv.w * wv.w;
    }
    ws[OFF_Q + (size_t)b * D_ + n] = acc + ipb[n];
}

// ---------------- qk[b,h,n] = sum_i q[b,h*64+i] * Wk[h*64+i, n] ----------------
// block: (h, nc, bc) -> stage Wk tile [64][256] in LDS, handle 8 batches
__global__ void k_qkc(const float* __restrict__ ipw, const float* __restrict__ ws_q,
                      float* __restrict__ ws) {
    int bid = blockIdx.x;
    int bc = bid & 3, nc = (bid >> 2) & 3, h = bid >> 4;
    int t = threadIdx.x;
    __shared__ float4 tile4[HD_ * 64];   // 64 rows x 256 cols floats = 64KB
    __shared__ float qall[8 * HD_];
    const float4* wk4 = (const float4*)(ipw + (size_t)D_ * D_);
#pragma unroll
    for (int j = 0; j < 16; ++j) {
        int lin4 = j * 256 + t;
        int i = lin4 >> 6, n4 = lin4 & 63;
        tile4[lin4] = wk4[(size_t)(h * HD_ + i) * 256 + nc * 64 + n4];
    }
#pragma unroll
    for (int j = 0; j < 2; ++j) {
        int idx = j * 256 + t;
        int bb = idx >> 6, i = idx & 63;
        qall[idx] = ws_q[(size_t)(bc * 8 + bb) * D_ + h * HD_ + i];
    }
    __syncthreads();
    const float* tile = (const float*)tile4;
#pragma unroll
    for (int bb = 0; bb < 8; ++bb) {
        float acc = 0.f;
#pragma unroll
        for (int i = 0; i < HD_; ++i) acc += qall[bb * HD_ + i] * tile[i * 256 + t];
        int b = bc * 8 + bb;
        ws[OFF_QK + (size_t)(b * H_ + h) * D_ + nc * 256 + t] = acc;
    }
}

// ---------------- ck[b,h] = q[b,h,:] . bk[h,:] ----------------
__global__ void k_ck(const float* __restrict__ ipb, const float* __restrict__ ws_q,
                     float* __restrict__ ws) {
    int b = blockIdx.x, t = threadIdx.x;
    __shared__ float qr[D_];
    for (int i = t; i < D_; i += 256) qr[i] = ws_q[(size_t)b * D_ + i];
    __syncthreads();
    int h = t >> 4, sub = t & 15;
    float acc = 0.f;
#pragma unroll
    for (int i = sub; i < HD_; i += 16) acc += qr[h * HD_ + i] * ipb[D_ + h * HD_ + i];
#pragma unroll
    for (int o = 8; o > 0; o >>= 1) acc += __shfl_xor(acc, o, 16);
    if (sub == 0) ws[OFF_CK + b * H_ + h] = acc;
}

// ---------------- pass 1: scores[b,h,s] = (x[b,s].qk[b,h] + cK)/8 ----------------
#define SROWS 64
#define XROWS 8
__global__ void k_scores(const float* __restrict__ xfeat, float* __restrict__ ws) {
    int bid = blockIdx.x;
    int b = bid / (S_ / SROWS);
    int sc = bid % (S_ / SROWS);
    int s0 = sc * SROWS;
    int t = threadIdx.x, w = t >> 6, l = t & 63;
    __shared__ float xs[XROWS][D_];

    const float* q0 = ws + OFF_QK + (size_t)(b * H_ + w * 4 + 0) * D_;
    const float* q1 = ws + OFF_QK + (size_t)(b * H_ + w * 4 + 1) * D_;
    const float* q2 = ws + OFF_QK + (size_t)(b * H_ + w * 4 + 2) * D_;
    const float* q3 = ws + OFF_QK + (size_t)(b * H_ + w * 4 + 3) * D_;
    float qkr0[16], qkr1[16], qkr2[16], qkr3[16];
#pragma unroll
    for (int k = 0; k < 16; ++k) {
        qkr0[k] = q0[k * 64 + l]; qkr1[k] = q1[k * 64 + l];
        qkr2[k] = q2[k * 64 + l]; qkr3[k] = q3[k * 64 + l];
    }
    float ck0 = ws[OFF_CK + b * H_ + w * 4 + 0];
    float ck1 = ws[OFF_CK + b * H_ + w * 4 + 1];
    float ck2 = ws[OFF_CK + b * H_ + w * 4 + 2];
    float ck3 = ws[OFF_CK + b * H_ + w * 4 + 3];

    for (int r0 = 0; r0 < SROWS; r0 += XROWS) {
        __syncthreads();
        const float4* src = (const float4*)(xfeat + ((size_t)b * S_ + s0 + r0) * D_);
        float4* dst = (float4*)&xs[0][0];
        for (int idx = t; idx < XROWS * D_ / 4; idx += 256) dst[idx] = src[idx];
        __syncthreads();
        for (int r = 0; r < XROWS; ++r) {
            float p0 = 0.f, p1 = 0.f, p2 = 0.f, p3 = 0.f;
#pragma unroll
            for (int k = 0; k < 16; ++k) {
                float xv = xs[r][k * 64 + l];
                p0 += xv * qkr0[k]; p1 += xv * qkr1[k];
                p2 += xv * qkr2[k]; p3 += xv * qkr3[k];
            }
#pragma unroll
            for (int o = 32; o > 0; o >>= 1) {
                p0 += __shfl_xor(p0, o); p1 += __shfl_xor(p1, o);
                p2 += __shfl_xor(p2, o); p3 += __shfl_xor(p3, o);
            }
            if (l < 4) {
                float p = (l == 0) ? (p0 + ck0) : (l == 1) ? (p1 + ck1) : (l == 2) ? (p2 + ck2) : (p3 + ck3);
                int h = w * 4 + l;
                ws[OFF_SC + (size_t)(b * H_ + h) * S_ + (s0 + r0 + r)] = p * 0.125f;
            }
        }
    }
}

// ---------------- softmax over S per (b,h) ----------------
__global__ void k_softmax(float* __restrict__ ws) {
    int t = threadIdx.x, w = t >> 6, l = t & 63;
    float* row = ws + OFF_SC + (size_t)blockIdx.x * S_;
    float4 a = ((float4*)row)[t];
    float4 c = ((float4*)row)[t + 256];
    __shared__ float sred[4];
    float mx = fmaxf(fmaxf(fmaxf(a.x, a.y), fmaxf(a.z, a.w)),
                     fmaxf(fmaxf(c.x, c.y), fmaxf(c.z, c.w)));
#pragma unroll
    for (int o = 32; o > 0; o >>= 1) mx = fmaxf(mx, __shfl_xor(mx, o));
    if (l == 0) sred[w] = mx;
    __syncthreads();
    mx = fmaxf(fmaxf(sred[0], sred[1]), fmaxf(sred[2], sred[3]));
    __syncthreads();
    a.x = __expf(a.x - mx); a.y = __expf(a.y - mx); a.z = __expf(a.z - mx); a.w = __expf(a.w - mx);
    c.x = __expf(c.x - mx); c.y = __expf(c.y - mx); c.z = __expf(c.z - mx); c.w = __expf(c.w - mx);
    float sum = a.x + a.y + a.z + a.w + c.x + c.y + c.z + c.w;
#pragma unroll
    for (int o = 32; o > 0; o >>= 1) sum += __shfl_xor(sum, o);
    if (l == 0) sred[w] = sum;
    __syncthreads();
    sum = sred[0] + sred[1] + sred[2] + sred[3];
    float inv = 1.f / sum;
    a.x *= inv; a.y *= inv; a.z *= inv; a.w *= inv;
    c.x *= inv; c.y *= inv; c.z *= inv; c.w *= inv;
    ((float4*)row)[t] = a; ((float4*)row)[t + 256] = c;
}

// ---------------- pass 2: partial xctx[b,h,:] = sum_s attn * x[b,s,:] ----------------
#define SCH 256
__global__ void k_xctx(const float* __restrict__ xfeat, float* __restrict__ ws) {
    int bid = blockIdx.x;
    int dc = bid & 3, sc = (bid >> 2) & 7, b = bid >> 5;
    int t = threadIdx.x, dg = t & 63, hg = t >> 6;
    int s0 = sc * SCH;
    __shared__ float wsm[SCH][16];
    const float* attn = ws + OFF_SC;
    for (int idx = t; idx < SCH * H_; idx += 256) {
        int h = idx >> 8;
        int s = idx & 255;
        wsm[s][h] = attn[(size_t)(b * H_ + h) * S_ + s0 + s];
    }
    __syncthreads();
    int d0 = dc * 256 + dg * 4;
    float4 acc0 = {0, 0, 0, 0}, acc1 = {0, 0, 0, 0}, acc2 = {0, 0, 0, 0}, acc3 = {0, 0, 0, 0};
    const float* xp = xfeat + ((size_t)b * S_ + s0) * D_ + d0;
    for (int s = 0; s < SCH; ++s) {
        float4 xv = *(const float4*)(xp + (size_t)s * D_);
        float4 wv = *(const float4*)&wsm[s][hg * 4];
        acc0.x += wv.x * xv.x; acc0.y += wv.x * xv.y; acc0.z += wv.x * xv.z; acc0.w += wv.x * xv.w;
        acc1.x += wv.y * xv.x; acc1.y += wv.y * xv.y; acc1.z += wv.y * xv.z; acc1.w += wv.y * xv.w;
        acc2.x += wv.z * xv.x; acc2.y += wv.z * xv.y; acc2.z += wv.z * xv.z; acc2.w += wv.z * xv.w;
        acc3.x += wv.w * xv.x; acc3.y += wv.w * xv.y; acc3.z += wv.w * xv.z; acc3.w += wv.w * xv.w;
    }
    float* pp = ws + OFF_PART + (((size_t)sc * B_ + b) * H_ + hg * 4) * D_ + d0;
    *(float4*)(pp) = acc0;
    *(float4*)(pp + D_) = acc1;
    *(float4*)(pp + 2 * D_) = acc2;
    *(float4*)(pp + 3 * D_) = acc3;
}

__global__ void k_xctx_reduce(float* __restrict__ ws) {
    int idx = blockIdx.x * 256 + threadIdx.x;
    float a = 0.f;
#pragma unroll
    for (int sc = 0; sc < 8; ++sc) a += ws[OFF_PART + (size_t)sc * (B_ * H_ * D_) + idx];
    ws[OFF_XCTX + idx] = a;
}

// ---------------- ctx[b, n] = Wv[n,:] . xctx[b, n>>6, :] + bv[n]  (GEMV style) ----------------
__global__ void k_ctx(const float* __restrict__ ipw, const float* __restrict__ ipb, float* __restrict__ ws) {
    int b = blockIdx.x >> 2, nc = blockIdx.x & 3;
    __shared__ float xr[4 * D_];   // 4 heads worth of xctx
    int t = threadIdx.x;
    for (int i = t; i < 4 * D_; i += 256)
        xr[i] = ws[OFF_XCTX + (size_t)(b * H_ + nc * 4) * D_ + i];
    __syncthreads();
    int n = nc * 256 + t;
    int hl = t >> 6;   // local head index within staged 4
    const float4* wr = (const float4*)(ipw + ((size_t)2 * D_ + n) * D_);
    const float4* xv4 = (const float4*)&xr[hl * D_];
    float acc = 0.f;
    for (int k = 0; k < D_ / 4; ++k) {
        float4 wv = wr[k];
        float4 xv = xv4[k];
        acc += xv.x * wv.x + xv.y * wv.y + xv.z * wv.z + xv.w * wv.w;
    }
    ws[OFF_CTX + (size_t)b * D_ + n] = acc + ipb[2 * D_ + n];
}

// ---------------- out = resid + scale*(invec @ W.T + bias)  (per-b row chunk) ----------------
__global__ void k_proj_res(const float* __restrict__ wmat, const float* __restrict__ bias,
                           const float* __restrict__ scale, const float* __restrict__ resid,
                           const float* __restrict__ invec, float* __restrict__ outvec) {
    int b = blockIdx.x >> 2, nc = blockIdx.x & 3;
    __shared__ float cx[D_];
    int t = threadIdx.x;
    for (int i = t; i < D_; i += 256) cx[i] = invec[(size_t)b * D_ + i];
    __syncthreads();
    int n = nc * 256 + t;
    const float4* wr = (const float4*)(wmat + (size_t)n * D_);
    float acc = 0.f;
    for (int k = 0; k < D_ / 4; ++k) {
        float4 wv = wr[k];
        float4 cv = *(const float4*)&cx[4 * k];
        acc += cv.x * wv.x + cv.y * wv.y + cv.z * wv.z + cv.w * wv.w;
    }
    outvec[(size_t)b * D_ + n] = resid[(size_t)b * D_ + n] + scale[0] * (acc + bias[n]);
}

// ---------------- layernorm over D (per b) ----------------
__global__ void k_ln(const float* __restrict__ inv, const float* __restrict__ g,
                     const float* __restrict__ bv, float* __restrict__ outv) {
    int b = blockIdx.x, t = threadIdx.x, w = t >> 6, l = t & 63;
    float4 v = ((const float4*)(inv + (size_t)b * D_))[t];
    float s = v.x + v.y + v.z + v.w;
    float s2 = v.x * v.x + v.y * v.y + v.z * v.z + v.w * v.w;
    __shared__ float sa[4], sb[4];
#pragma unroll
    for (int o = 32; o > 0; o >>= 1) { s += __shfl_xor(s, o); s2 += __shfl_xor(s2, o); }
    if (l == 0) { sa[w] = s; sb[w] = s2; }
    __syncthreads();
    s = sa[0] + sa[1] + sa[2] + sa[3];
    s2 = sb[0] + sb[1] + sb[2] + sb[3];
    float mu = s * (1.f / (float)D_);
    float var = s2 * (1.f / (float)D_) - mu * mu;
    float rs = rsqrtf(var + EPS_);
    float4 gg = ((const float4*)g)[t], bb = ((const float4*)bv)[t];
    float4 o4;
    o4.x = (v.x - mu) * rs * gg.x + bb.x;
    o4.y = (v.y - mu) * rs * gg.y + bb.y;
    o4.z = (v.z - mu) * rs * gg.z + bb.z;
    o4.w = (v.w - mu) * rs * gg.w + bb.w;
    ((float4*)(outv + (size_t)b * D_))[t] = o4;
}

// ---------------- spectral: 16-mode DFT of z1, filter, synthesize ----------------
__global__ void k_spec(float* __restrict__ ws) {
    int b = blockIdx.x, t = threadIdx.x;
    __shared__ float zr[D_];
    __shared__ float cre[MODES_], cim[MODES_];
    const float* z1 = ws + OFF_Z1 + (size_t)b * D_;
    for (int i = t; i < D_; i += 256) zr[i] = z1[i];
    __syncthreads();
    const float step = 6.283185307179586f / (float)D_;
    int m = t >> 4, sub = t & 15;
    float ar = 0.f, ai = 0.f;
    for (int n = sub; n < D_; n += 16) {
        int idx = (m * n) & (D_ - 1);
        float sn, cs;
        __sincosf(step * (float)idx, &sn, &cs);
        float z = zr[n];
        ar += z * cs; ai -= z * sn;
    }
#pragma unroll
    for (int o = 8; o > 0; o >>= 1) { ar += __shfl_xor(ar, o, 16); ai += __shfl_xor(ai, o, 16); }
    if (sub == 0) {
        float fr = ws[OFF_FILT_RE + m], fi = ws[OFF_FILT_IM + m];
        cre[m] = (fr * ar - fi * ai) * (1.f / (float)D_);
        cim[m] = (fr * ai + fi * ar) * (1.f / (float)D_);
    }
    __syncthreads();
    for (int n = t; n < D_; n += 256) {
        float acc = 0.f;
#pragma unroll
        for (int mm = 0; mm < MODES_; ++mm) {
            int idx = (mm * n) & (D_ - 1);
            float sn, cs;
            __sincosf(step * (float)idx, &sn, &cs);
            acc += cre[mm] * cs - cim[mm] * sn;
        }
        ws[OFF_ZSP + (size_t)b * D_ + n] = acc;
    }
}

// ---------------- LN2 + gate mix -> z3 ----------------
__global__ void k_ln2gate(const float* __restrict__ zprev, const float* __restrict__ g2,
                          const float* __restrict__ b2v, const float* __restrict__ gate,
                          float* __restrict__ ws) {
    int b = blockIdx.x, t = threadIdx.x, w = t >> 6, l = t & 63;
    float4 v = ((const float4*)(ws + OFF_R2 + (size_t)b * D_))[t];
    float s = v.x + v.y + v.z + v.w;
    float s2 = v.x * v.x + v.y * v.y + v.z * v.z + v.w * v.w;
    __shared__ float sa[4], sb[4];
#pragma unroll
    for (int o = 32; o > 0; o >>= 1) { s += __shfl_xor(s, o); s2 += __shfl_xor(s2, o); }
    if (l == 0) { sa[w] = s; sb[w] = s2; }
    __syncthreads();
    s = sa[0] + sa[1] + sa[2] + sa[3];
    s2 = sb[0] + sb[1] + sb[2] + sb[3];
    float mu = s * (1.f / (float)D_);
    float var = s2 * (1.f / (float)D_) - mu * mu;
    float rs = rsqrtf(var + EPS_);
    float4 gg = ((const float4*)g2)[t], bb = ((const float4*)b2v)[t];
    float gsig = 1.f / (1.f + __expf(-gate[0]));
    float4 zp = ((const float4*)(zprev + (size_t)b * D_))[t];
    float4 z3;
    z3.x = gsig * ((v.x - mu) * rs * gg.x + bb.x) + (1.f - gsig) * zp.x;
    z3.y = gsig * ((v.y - mu) * rs * gg.y + bb.y) + (1.f - gsig) * zp.y;
    z3.z = gsig * ((v.z - mu) * rs * gg.z + bb.z) + (1.f - gsig) * zp.z;
    z3.w = gsig * ((v.w - mu) * rs * gg.w + bb.w) + (1.f - gsig) * zp.w;
    ((float4*)(ws + OFF_Z3 + (size_t)b * D_))[t] = z3;
}

// ---------------- batchnorm over B per column ----------------
__global__ void k_bn(const float* __restrict__ bng, const float* __restrict__ bnb,
                     const float* __restrict__ ws, float* __restrict__ out) {
    int d = blockIdx.x * 256 + threadIdx.x;
    float vals[B_];
    float s = 0.f, s2 = 0.f;
#pragma unroll
    for (int b = 0; b < B_; ++b) {
        float v = ws[OFF_Z3 + (size_t)b * D_ + d];
        vals[b] = v; s += v; s2 += v * v;
    }
    float mu = s * (1.f / (float)B_);
    float var = s2 * (1.f / (float)B_) - mu * mu;
    float rs = rsqrtf(var + EPS_);
    float gg = bng[d], bb = bnb[d];
#pragma unroll
    for (int b = 0; b < B_; ++b) out[(size_t)b * D_ + d] = (vals[b] - mu) * rs * gg + bb;
}

extern "C" void kernel_launch(void* const* d_in, const int* in_sizes, int n_in,
                              void* d_out, int out_size, void* d_ws, size_t ws_size,
                              hipStream_t stream) {
    const float* x_feat = (const float*)d_in[0];
    const float* z_prev = (const float*)d_in[1];
    const float* ipw    = (const float*)d_in[2];
    const float* ipb    = (const float*)d_in[3];
    const float* wout   = (const float*)d_in[4];
    const float* bout   = (const float*)d_in[5];
    const float* ln1g   = (const float*)d_in[6];
    const float* ln1b   = (const float*)d_in[7];
    const float* ln2g   = (const float*)d_in[8];
    const float* ln2b   = (const float*)d_in[9];
    const float* sreal  = (const float*)d_in[10];
    const float* simag  = (const float*)d_in[11];
    const float* pw     = (const float*)d_in[12];
    const float* pb     = (const float*)d_in[13];
    const float* bng    = (const float*)d_in[14];
    const float* bnb    = (const float*)d_in[15];
    const float* gate   = (const float*)d_in[16];
    const float* sattn  = (const float*)d_in[17];
    const float* sden   = (const float*)d_in[18];
    float* ws  = (float*)d_ws;
    float* out = (float*)d_out;

    k_filt<<<MODES_, 256, 0, stream>>>(sreal, simag, ws);
    k_q<<<B_ * 4, 256, 0, stream>>>(z_prev, ipw, ipb, ws);
    k_qkc<<<H_ * 16, 256, 0, stream>>>(ipw, ws + OFF_Q, ws);
    k_ck<<<B_, 256, 0, stream>>>(ipb, ws + OFF_Q, ws);
    k_scores<<<B_ * (S_ / SROWS), 256, 0, stream>>>(x_feat, ws);
    k_softmax<<<B_ * H_, 256, 0, stream>>>(ws);
    k_xctx<<<B_ * 4 * 8, 256, 0, stream>>>(x_feat, ws);
    k_xctx_reduce<<<(B_ * H_ * D_) / 256, 256, 0, stream>>>(ws);
    k_ctx<<<B_ * 4, 256, 0, stream>>>(ipw, ipb, ws);
    k_proj_res<<<B_ * 4, 256, 0, stream>>>(wout, bout, sattn, z_prev, ws + OFF_CTX, ws + OFF_R1);
    k_ln<<<B_, 256, 0, stream>>>(ws + OFF_R1, ln1g, ln1b, ws + OFF_Z1);
    k_spec<<<B_, 256, 0, stream>>>(ws);
    k_proj_res<<<B_ * 4, 256, 0, stream>>>(pw, pb, sden, ws + OFF_Z1, ws + OFF_ZSP, ws + OFF_R2);
    k_ln2gate<<<B_, 256, 0, stream>>>(z_prev, ln2g, ln2b, gate, ws);
    k_bn<<<D_ / 256, 256, 0, stream>>>(bng, bnb, ws, out);
}